// Round 5
// baseline (7757.227 us; speedup 1.0000x reference)
//
#include <hip/hip_runtime.h>

// ---------------------------------------------------------------------------
// Round 4: correctness anchor. ALL tensors float32 (per reference + harness
// header). Pure fp32 VALU arithmetic, barriers between every LDS stage,
// zero workspace. MFMA comes back once this is green.
// ---------------------------------------------------------------------------

// Kernel 1: per (window, head) block, 256 threads.
//   kv slice (49x64) -> LDS, S=QK^T*scale+bias -> LDS, softmax, X=PV -> d_out.
__global__ void naive_attn(const float* __restrict__ inp, const float* __restrict__ qg,
                           const float* __restrict__ W, const float* __restrict__ b,
                           const float* __restrict__ bt, float* __restrict__ out) {
    __shared__ float kv_s[49][66];   // [token][c]: c<32 -> k_d, c>=32 -> v_(c-32)
    __shared__ float S_s[49][52];    // scores, then P in place
    const int win = blockIdx.x;      // 0..1023
    const int h   = blockIdx.y;      // 0..15
    const int t   = threadIdx.x;     // 0..255

    // ---- phase 1: kv slice = inp[win] @ qkv_w[:, head cols] + qkv_b ----
    // n wave-uniform (broadcast inp reads), c lane-consecutive (coalesced W reads)
    for (int o = t; o < 49 * 64; o += 256) {
        int n = o >> 6, c = o & 63;
        int col = (c < 32) ? (h * 32 + c) : (512 + h * 32 + (c - 32));
        float acc = b[col];
        const float* ar = inp + ((size_t)win * 49 + n) * 512;
        const float* wc = W + col;
        for (int kk = 0; kk < 512; kk++)
            acc += ar[kk] * wc[(size_t)kk << 10];
        kv_s[n][c] = acc;
    }
    __syncthreads();

    // ---- phase 2: S[i][j] = scale * q_i . k_j + bias(rel(i,j)) ----
    const float scale = 0.17677669529663687f;  // 1/sqrt(32)
    for (int o = t; o < 49 * 49; o += 256) {
        int i = o / 49, j = o - i * 49;
        const float* qr = qg + ((size_t)(win >> 4) * 49 + i) * 512 + h * 32;
        float acc = 0.f;
        for (int d = 0; d < 32; d++)
            acc += qr[d] * kv_s[j][d];
        int idx = (i / 7 - j / 7 + 6) * 13 + (i % 7 - j % 7 + 6);
        S_s[i][j] = acc * scale + bt[idx * 16 + h];
    }
    __syncthreads();

    // ---- softmax per row (thread t handles row t) ----
    if (t < 49) {
        float mx = -1e30f;
        for (int j = 0; j < 49; j++) mx = fmaxf(mx, S_s[t][j]);
        float sum = 0.f;
        for (int j = 0; j < 49; j++) {
            float e = __expf(S_s[t][j] - mx);
            S_s[t][j] = e; sum += e;
        }
        float inv = 1.f / sum;
        for (int j = 0; j < 49; j++) S_s[t][j] *= inv;
    }
    __syncthreads();

    // ---- phase 3: X[i][d] = sum_j P[i][j] * v[j][d] -> d_out ----
    for (int o = t; o < 49 * 32; o += 256) {
        int i = o >> 5, d = o & 31;
        float acc = 0.f;
        for (int j = 0; j < 49; j++)
            acc += S_s[i][j] * kv_s[j][32 + d];
        out[((size_t)win * 49 + i) * 512 + h * 32 + d] = acc;
    }
}

// Kernel 2: in-place out = out @ proj_w + proj_b. Each block owns 16 disjoint
// rows; stages ALL its rows into LDS, barrier, then computes+writes. Race-free.
__global__ void naive_proj(const float* __restrict__ pw, const float* __restrict__ pb,
                           float* __restrict__ io) {
    __shared__ float Xs[16][520];    // 33,280 B
    const int m0 = blockIdx.x * 16;
    const int t = threadIdx.x;

    // stage 16x512 f32 rows (2048 float4 loads)
    for (int o = t; o < 16 * 128; o += 256) {
        int row = o >> 7, col4 = (o & 127) << 2;
        *(float4*)(&Xs[row][col4]) = *(const float4*)(io + ((size_t)(m0 + row)) * 512 + col4);
    }
    __syncthreads();

    for (int r = 0; r < 16; r++) {
        for (int cb = 0; cb < 512; cb += 256) {
            int col = cb + t;
            float acc = pb[col];
            const float* wc = pw + col;
            for (int kk = 0; kk < 512; kk++)
                acc += Xs[r][kk] * wc[(size_t)kk << 9];
            io[((size_t)(m0 + r)) * 512 + col] = acc;
        }
    }
}

// ---------------------------------------------------------------------------
extern "C" void kernel_launch(void* const* d_in, const int* in_sizes, int n_in,
                              void* d_out, int out_size, void* d_ws, size_t ws_size,
                              hipStream_t stream) {
    const float* inputs = (const float*)d_in[0];   // [1024*49, 512]
    const float* qg     = (const float*)d_in[1];   // [64*49, 512]
    const float* qkv_w  = (const float*)d_in[2];   // [512, 1024]
    const float* qkv_b  = (const float*)d_in[3];   // [1024]
    const float* btab   = (const float*)d_in[4];   // [169, 16]
    const float* proj_w = (const float*)d_in[5];   // [512, 512]
    const float* proj_b = (const float*)d_in[6];   // [512]
    float* out = (float*)d_out;                    // [1024*49, 512]
    (void)d_ws; (void)ws_size;                     // zero-workspace design

    naive_attn<<<dim3(1024, 16), 256, 0, stream>>>(inputs, qg, qkv_w, qkv_b, btab, out);
    naive_proj<<<50176 / 16, 256, 0, stream>>>(proj_w, proj_b, out);
}